// Round 8
// baseline (350.969 us; speedup 1.0000x reference)
//
#include <hip/hip_runtime.h>

#define N_NODES 100000
#define N_EDGES 640000
#define D 128
#define NLAYERS 4

typedef __attribute__((ext_vector_type(8))) short short8;
typedef __attribute__((ext_vector_type(4))) float f32x4;

// f32 -> bf16 with round-to-nearest-even
__device__ __forceinline__ unsigned short cvbf(float f) {
    unsigned u = __float_as_uint(f);
    return (unsigned short)((u + 0x7fffu + ((u >> 16) & 1u)) >> 16);
}

// ---------------- CSR build ----------------
__global__ void count_kernel(const int* __restrict__ edge, int* __restrict__ cnt) {
    int e = blockIdx.x * 256 + threadIdx.x;
    if (e < N_EDGES) atomicAdd(&cnt[edge[N_EDGES + e]], 1);
}

__global__ void scan_local(const int* __restrict__ cnt, int* __restrict__ rp,
                           int* __restrict__ bsum) {
    __shared__ int tsum[256];
    int t = threadIdx.x;
    int base = blockIdx.x * 1024 + t * 4;
    int v[4];
#pragma unroll
    for (int j = 0; j < 4; ++j) {
        int i = base + j;
        v[j] = (i < N_NODES) ? cnt[i] : 0;
    }
    int ts = v[0] + v[1] + v[2] + v[3];
    tsum[t] = ts;
    __syncthreads();
    for (int off = 1; off < 256; off <<= 1) {
        int add = (t >= off) ? tsum[t - off] : 0;
        __syncthreads();
        tsum[t] += add;
        __syncthreads();
    }
    int incl = tsum[t];
    int run = incl - ts;
#pragma unroll
    for (int j = 0; j < 4; ++j) {
        int i = base + j;
        if (i < N_NODES) rp[i] = run;
        run += v[j];
    }
    if (t == 255) bsum[blockIdx.x] = incl;
}

__global__ void scan_bsums(int* __restrict__ bsum, int nblocks) {
    if (threadIdx.x == 0 && blockIdx.x == 0) {
        int run = 0;
        for (int b = 0; b < nblocks; ++b) {
            int v = bsum[b];
            bsum[b] = run;
            run += v;
        }
    }
}

__global__ void scan_add(int* __restrict__ rp, int* __restrict__ fill,
                         const int* __restrict__ bsum) {
    int add = bsum[blockIdx.x];
    int base = blockIdx.x * 1024;
#pragma unroll
    for (int j = 0; j < 4; ++j) {
        int i = base + j * 256 + threadIdx.x;
        if (i < N_NODES) {
            int v = rp[i] + add;
            rp[i] = v;
            fill[i] = v;
        }
    }
    if (blockIdx.x == 0 && threadIdx.x == 0) rp[N_NODES] = N_EDGES;
}

__global__ void fill_kernel(const int* __restrict__ edge, int* __restrict__ fill,
                            int* __restrict__ col) {
    int e = blockIdx.x * 256 + threadIdx.x;
    if (e < N_EDGES) {
        int dst = edge[N_EDGES + e];
        int slot = atomicAdd(&fill[dst], 1);
        col[slot] = edge[e];
    }
}

// ---------------- weight fp32 -> bf16 ----------------
__global__ void wconv(const float* __restrict__ in, unsigned short* __restrict__ out, int n4) {
    int i = blockIdx.x * 256 + threadIdx.x;
    if (i < n4) {
        float4 v = ((const float4*)in)[i];
        ushort4 o;
        o.x = cvbf(v.x);
        o.y = cvbf(v.y);
        o.z = cvbf(v.z);
        o.w = cvbf(v.w);
        ((ushort4*)out)[i] = o;
    }
}

// ---------------- input projection: outf = x @ W1^T + b1 (+ bf16 mirror) ----------------
__global__ __launch_bounds__(256, 4) void proj_k(const float* __restrict__ Asrc,
                                                 const short* __restrict__ W1b,
                                                 const float* __restrict__ b1,
                                                 float* __restrict__ outf,
                                                 unsigned short* __restrict__ outb, int nrows) {
    __shared__ __align__(16) char smem[32768];
    short8* As = (short8*)smem;   // 16 KB
    float* Of = (float*)smem;     // 32 KB after barrier
    int t = threadIdx.x;
    int rowbase = blockIdx.x * 64;

#pragma unroll
    for (int ch = 0; ch < 4; ++ch) {
        int flat = ch * 256 + t;
        int r = flat >> 4, g = flat & 15;
        int gr = rowbase + r;
        short8 frag = {0, 0, 0, 0, 0, 0, 0, 0};
        if (gr < nrows) {
            const float4* src = (const float4*)Asrc;
            float4 a0 = src[(size_t)gr * 32 + g * 2];
            float4 a1 = src[(size_t)gr * 32 + g * 2 + 1];
            frag[0] = (short)cvbf(a0.x);
            frag[1] = (short)cvbf(a0.y);
            frag[2] = (short)cvbf(a0.z);
            frag[3] = (short)cvbf(a0.w);
            frag[4] = (short)cvbf(a1.x);
            frag[5] = (short)cvbf(a1.y);
            frag[6] = (short)cvbf(a1.z);
            frag[7] = (short)cvbf(a1.w);
        }
        As[r * 16 + (g ^ (r & 7))] = frag;
    }

    int lane = t & 63;
    int w = t >> 6;
    int c0 = w * 32;
    int lrow = lane & 15;
    int lk = lane >> 4;
    int swz = lrow & 7;

    const short8* W1v = (const short8*)W1b;
    short8 bw[2][4];
#pragma unroll
    for (int ct = 0; ct < 2; ++ct)
#pragma unroll
        for (int ks = 0; ks < 4; ++ks)
            bw[ct][ks] = W1v[(size_t)(c0 + ct * 16 + lrow) * 16 + ks * 4 + lk];

    __syncthreads();

    f32x4 zero4 = {0.f, 0.f, 0.f, 0.f};
    f32x4 acc[4][2];
#pragma unroll
    for (int rt = 0; rt < 4; ++rt) {
        acc[rt][0] = zero4;
        acc[rt][1] = zero4;
    }
#pragma unroll
    for (int ks = 0; ks < 4; ++ks) {
        short8 a[4];
#pragma unroll
        for (int rt = 0; rt < 4; ++rt)
            a[rt] = As[(rt * 16 + lrow) * 16 + ((ks * 4 + lk) ^ swz)];
#pragma unroll
        for (int rt = 0; rt < 4; ++rt) {
            acc[rt][0] = __builtin_amdgcn_mfma_f32_16x16x32_bf16(a[rt], bw[0][ks], acc[rt][0], 0, 0, 0);
            acc[rt][1] = __builtin_amdgcn_mfma_f32_16x16x32_bf16(a[rt], bw[1][ks], acc[rt][1], 0, 0, 0);
        }
    }

    float b1v[2] = {b1[c0 + lrow], b1[c0 + 16 + lrow]};
    __syncthreads();
#pragma unroll
    for (int rt = 0; rt < 4; ++rt) {
#pragma unroll
        for (int ct = 0; ct < 2; ++ct) {
            int c = c0 + ct * 16 + lrow;
#pragma unroll
            for (int reg = 0; reg < 4; ++reg) {
                int row = rt * 16 + lk * 4 + reg;
                Of[row * 128 + ((c + ((row >> 2) & 3) * 8) & 127)] = acc[rt][ct][reg] + b1v[ct];
            }
        }
    }
    __syncthreads();

#pragma unroll
    for (int ch = 0; ch < 8; ++ch) {
        int f = ch * 256 + t;
        int row = f >> 5;
        int c4 = f & 31;
        int grow = rowbase + row;
        if (grow >= nrows) continue;
        int pc4 = (c4 + ((row >> 2) & 3) * 2) & 31;
        float4 o = *(const float4*)&Of[row * 128 + pc4 * 4];
        ((float4*)outf)[(size_t)grow * 32 + c4] = o;
        ushort4 ob;
        ob.x = cvbf(o.x);
        ob.y = cvbf(o.y);
        ob.z = cvbf(o.z);
        ob.w = cvbf(o.w);
        ((ushort4*)outb)[(size_t)grow * 32 + c4] = ob;
    }
}

// ---------------- fused GNN layer ----------------
// Gather phase: flat-edge walk. Each wave owns 16 nodes whose edges are one
// contiguous, dst-sorted col[] range (CSR). One gather per edge (no masked-
// iteration waste), 16-deep load pipeline, accumulate in one register pair,
// flush node sums (inv_deg-scaled bf16) into the swizzled As tile at uniform
// node-boundary crossings (scalar rp loads). Then T = As@W1^T + b1*(deg>0),
// out = Hin + relu(T@W2^T + b2) with LDS-staged coalesced epilogue.
// RACE NOTE: bf16 mirror ping-pongs across layers (hb_out != hb_in).
__global__ __launch_bounds__(256, 4) void gnnlayer_k(
    const unsigned* __restrict__ hb_in, const int* __restrict__ rp, const int* __restrict__ col,
    const int* __restrict__ cnt, const short* __restrict__ W1b, const float* __restrict__ b1,
    const short* __restrict__ W2b, const float* __restrict__ b2, const float* __restrict__ Hin,
    float* __restrict__ outf, unsigned short* __restrict__ hb_out, int nrows) {
    __shared__ __align__(16) char smem[32768];
    __shared__ float dflag[64];
    short8* As = (short8*)smem;            // 16 KB aggregated A tile (bf16, swizzled)
    short8* Ts = (short8*)(smem + 16384);  // 16 KB T tile
    float* Of = (float*)smem;              // 32 KB fp32 output tile (after barrier)
    int t = threadIdx.x;
    int rowbase = blockIdx.x * 64;
    int lane = t & 63;
    int wv = __builtin_amdgcn_readfirstlane(t >> 6);  // 0..3

    // ---- flat-edge gather-aggregate: this wave owns nodes nbase..nbase+16 ----
    {
        constexpr int U = 16;
        int nbase = rowbase + wv * 16;
        unsigned* AsU = (unsigned*)As;
        int g = lane >> 2;
        int dw = lane & 3;

        int startj = __builtin_amdgcn_readfirstlane(rp[min(nbase, N_NODES)]);
        int endT = __builtin_amdgcn_readfirstlane(rp[min(nbase + 16, N_NODES)]);
        int T = endT - startj;

        int cur = 0;                      // current node within the 16 (uniform)
        int cur_start = startj;           // absolute edge range of current node
        int cur_end = __builtin_amdgcn_readfirstlane(rp[min(nbase + 1, N_NODES)]);
        float ax = 0.f, ay = 0.f;

        int u[U];
#pragma unroll
        for (int k = 0; k < U; ++k) u[k] = (k < T) ? col[startj + k] : 0;

        for (int jg = 0; jg < T; jg += U) {
            unsigned p[U];
            // issue all gathers of this group first (U independent loads in flight)
#pragma unroll
            for (int k = 0; k < U; ++k)
                p[k] = (jg + k < T) ? hb_in[(size_t)u[k] * 64 + lane] : 0u;
            // prefetch next group's col indices (overlaps gather latency)
#pragma unroll
            for (int k = 0; k < U; ++k) {
                int jn = jg + U + k;
                if (jn < T) u[k] = col[startj + jn];
            }
            // accumulate; flush at node boundaries (wave-uniform control)
#pragma unroll
            for (int k = 0; k < U; ++k) {
                int ja = startj + jg + k;  // absolute edge index
                if (jg + k >= T) break;
                while (ja >= cur_end) {
                    float inv = 1.0f / fmaxf((float)(cur_end - cur_start), 1.0f);
                    unsigned pv =
                        ((unsigned)cvbf(ay * inv) << 16) | (unsigned)cvbf(ax * inv);
                    int r = wv * 16 + cur;
                    AsU[(r * 16 + (g ^ (r & 7))) * 4 + dw] = pv;
                    ax = 0.f;
                    ay = 0.f;
                    ++cur;
                    cur_start = cur_end;
                    cur_end = __builtin_amdgcn_readfirstlane(rp[min(nbase + cur + 1, N_NODES)]);
                }
                ax += __uint_as_float(p[k] << 16);
                ay += __uint_as_float(p[k] & 0xffff0000u);
            }
        }
        // flush remaining nodes (incl. zero-degree tail)
        while (cur < 16) {
            float inv = 1.0f / fmaxf((float)(cur_end - cur_start), 1.0f);
            unsigned pv = ((unsigned)cvbf(ay * inv) << 16) | (unsigned)cvbf(ax * inv);
            int r = wv * 16 + cur;
            AsU[(r * 16 + (g ^ (r & 7))) * 4 + dw] = pv;
            ax = 0.f;
            ay = 0.f;
            ++cur;
            cur_start = cur_end;
            cur_end = __builtin_amdgcn_readfirstlane(rp[min(nbase + cur + 1, N_NODES)]);
        }
    }
    if (t < 64) {
        int gr = rowbase + t;
        dflag[t] = (gr < nrows && cnt[gr] > 0) ? 1.0f : 0.0f;
    }

    int w = wv;
    int c0 = w * 32;
    int lrow = lane & 15;
    int lk = lane >> 4;
    int swz = lrow & 7;

    const short8* W1v = (const short8*)W1b;
    short8 bw[2][4];
#pragma unroll
    for (int ct = 0; ct < 2; ++ct)
#pragma unroll
        for (int ks = 0; ks < 4; ++ks)
            bw[ct][ks] = W1v[(size_t)(c0 + ct * 16 + lrow) * 16 + ks * 4 + lk];

    __syncthreads();

    f32x4 zero4 = {0.f, 0.f, 0.f, 0.f};
    f32x4 acc[4][2];
#pragma unroll
    for (int rt = 0; rt < 4; ++rt) {
        acc[rt][0] = zero4;
        acc[rt][1] = zero4;
    }
#pragma unroll
    for (int ks = 0; ks < 4; ++ks) {
        short8 a[4];
#pragma unroll
        for (int rt = 0; rt < 4; ++rt)
            a[rt] = As[(rt * 16 + lrow) * 16 + ((ks * 4 + lk) ^ swz)];
#pragma unroll
        for (int rt = 0; rt < 4; ++rt) {
            acc[rt][0] = __builtin_amdgcn_mfma_f32_16x16x32_bf16(a[rt], bw[0][ks], acc[rt][0], 0, 0, 0);
            acc[rt][1] = __builtin_amdgcn_mfma_f32_16x16x32_bf16(a[rt], bw[1][ks], acc[rt][1], 0, 0, 0);
        }
    }

    const short8* W2v = (const short8*)W2b;
    short8 bw2[2][4];
#pragma unroll
    for (int ct = 0; ct < 2; ++ct)
#pragma unroll
        for (int ks = 0; ks < 4; ++ks)
            bw2[ct][ks] = W2v[(size_t)(c0 + ct * 16 + lrow) * 16 + ks * 4 + lk];

    float b1v[2] = {b1[c0 + lrow], b1[c0 + 16 + lrow]};
    short* TsS = (short*)Ts;
#pragma unroll
    for (int rt = 0; rt < 4; ++rt) {
#pragma unroll
        for (int ct = 0; ct < 2; ++ct) {
            int c = c0 + ct * 16 + lrow;
            int gh = c >> 3;
#pragma unroll
            for (int reg = 0; reg < 4; ++reg) {
                int rl = rt * 16 + lk * 4 + reg;  // C/D: row=(lane>>4)*4+reg
                float tv = acc[rt][ct][reg] + b1v[ct] * dflag[rl];
                TsS[rl * 128 + ((gh ^ (rl & 7)) << 3) + (c & 7)] = (short)cvbf(tv);
            }
        }
    }
    __syncthreads();

    f32x4 acc2[4][2];
#pragma unroll
    for (int rt = 0; rt < 4; ++rt) {
        acc2[rt][0] = zero4;
        acc2[rt][1] = zero4;
    }
#pragma unroll
    for (int ks = 0; ks < 4; ++ks) {
        short8 a[4];
#pragma unroll
        for (int rt = 0; rt < 4; ++rt)
            a[rt] = Ts[(rt * 16 + lrow) * 16 + ((ks * 4 + lk) ^ swz)];
#pragma unroll
        for (int rt = 0; rt < 4; ++rt) {
            acc2[rt][0] = __builtin_amdgcn_mfma_f32_16x16x32_bf16(a[rt], bw2[0][ks], acc2[rt][0], 0, 0, 0);
            acc2[rt][1] = __builtin_amdgcn_mfma_f32_16x16x32_bf16(a[rt], bw2[1][ks], acc2[rt][1], 0, 0, 0);
        }
    }

    float b2v[2] = {b2[c0 + lrow], b2[c0 + 16 + lrow]};
    __syncthreads();  // As/Ts dead; Of takes over
#pragma unroll
    for (int rt = 0; rt < 4; ++rt) {
#pragma unroll
        for (int ct = 0; ct < 2; ++ct) {
            int c = c0 + ct * 16 + lrow;
#pragma unroll
            for (int reg = 0; reg < 4; ++reg) {
                int row = rt * 16 + lk * 4 + reg;
                Of[row * 128 + ((c + ((row >> 2) & 3) * 8) & 127)] = acc2[rt][ct][reg] + b2v[ct];
            }
        }
    }
    __syncthreads();

    const float4* Hin4 = (const float4*)Hin;
#pragma unroll
    for (int ch = 0; ch < 8; ++ch) {
        int f = ch * 256 + t;
        int row = f >> 5;
        int c4 = f & 31;
        int grow = rowbase + row;
        if (grow >= nrows) continue;
        int pc4 = (c4 + ((row >> 2) & 3) * 2) & 31;
        float4 v = *(const float4*)&Of[row * 128 + pc4 * 4];
        float4 hv = Hin4[(size_t)grow * 32 + c4];
        float4 o;
        o.x = hv.x + fmaxf(v.x, 0.f);
        o.y = hv.y + fmaxf(v.y, 0.f);
        o.z = hv.z + fmaxf(v.z, 0.f);
        o.w = hv.w + fmaxf(v.w, 0.f);
        ((float4*)outf)[(size_t)grow * 32 + c4] = o;
        if (hb_out) {
            ushort4 ob;
            ob.x = cvbf(o.x);
            ob.y = cvbf(o.y);
            ob.z = cvbf(o.z);
            ob.w = cvbf(o.w);
            ((ushort4*)hb_out)[(size_t)grow * 32 + c4] = ob;
        }
    }
}

extern "C" void kernel_launch(void* const* d_in, const int* in_sizes, int n_in,
                              void* d_out, int out_size, void* d_ws, size_t ws_size,
                              hipStream_t stream) {
    const float* x = (const float*)d_in[0];
    const float* Wi = (const float*)d_in[1];
    const float* bi = (const float*)d_in[2];
    const float* Wm = (const float*)d_in[3];
    const float* bm = (const float*)d_in[4];
    const float* Wu = (const float*)d_in[5];
    const float* bu = (const float*)d_in[6];
    const int* edge = (const int*)d_in[7];
    float* h = (float*)d_out;

    char* ws = (char*)d_ws;
    size_t off = 0;
    auto alloc = [&](size_t bytes) {
        void* p = ws + off;
        off += (bytes + 255) & ~(size_t)255;
        return p;
    };
    // ping-pong bf16 mirrors of h (avoids cross-block RAW race in fused layers)
    unsigned short* hbuf[2];
    hbuf[0] = (unsigned short*)alloc((size_t)N_NODES * D * 2);
    hbuf[1] = (unsigned short*)alloc((size_t)N_NODES * D * 2);
    unsigned short* Wi_bf = (unsigned short*)alloc((size_t)D * D * 2);
    unsigned short* Wm_bf = (unsigned short*)alloc((size_t)NLAYERS * D * D * 2);
    unsigned short* Wu_bf = (unsigned short*)alloc((size_t)NLAYERS * D * D * 2);
    int* cnt = (int*)alloc((size_t)N_NODES * sizeof(int));
    int* rp = (int*)alloc((size_t)(N_NODES + 1) * sizeof(int));
    int* fill = (int*)alloc((size_t)N_NODES * sizeof(int));
    int* bsum = (int*)alloc(1024 * sizeof(int));
    int* col = (int*)alloc((size_t)N_EDGES * sizeof(int));

    const int scan_blocks = (N_NODES + 1023) / 1024;  // 98
    const int edge_blocks = (N_EDGES + 255) / 256;    // 2500
    const int gemm_blocks = (N_NODES + 63) / 64;      // 1563

    // CSR build
    hipMemsetAsync(cnt, 0, (size_t)N_NODES * sizeof(int), stream);
    count_kernel<<<edge_blocks, 256, 0, stream>>>(edge, cnt);
    scan_local<<<scan_blocks, 256, 0, stream>>>(cnt, rp, bsum);
    scan_bsums<<<1, 64, 0, stream>>>(bsum, scan_blocks);
    scan_add<<<scan_blocks, 256, 0, stream>>>(rp, fill, bsum);
    fill_kernel<<<edge_blocks, 256, 0, stream>>>(edge, fill, col);

    // weights -> bf16
    wconv<<<(D * D / 4 + 255) / 256, 256, 0, stream>>>(Wi, Wi_bf, D * D / 4);
    wconv<<<(NLAYERS * D * D / 4 + 255) / 256, 256, 0, stream>>>(Wm, Wm_bf, NLAYERS * D * D / 4);
    wconv<<<(NLAYERS * D * D / 4 + 255) / 256, 256, 0, stream>>>(Wu, Wu_bf, NLAYERS * D * D / 4);

    // input projection: h = x @ Wi^T + bi  (fp32 out + bf16 mirror into hbuf[0])
    proj_k<<<gemm_blocks, 256, 0, stream>>>(x, (const short*)Wi_bf, bi, h, hbuf[0], N_NODES);

    for (int l = 0; l < NLAYERS; ++l) {
        // read mirror hbuf[l&1], write mirror hbuf[(l+1)&1] (none on last layer)
        unsigned short* mirror = (l == NLAYERS - 1) ? nullptr : hbuf[(l + 1) & 1];
        gnnlayer_k<<<gemm_blocks, 256, 0, stream>>>(
            (const unsigned*)hbuf[l & 1], rp, col, cnt,
            (const short*)(Wm_bf + (size_t)l * D * D), bm + (size_t)l * D,
            (const short*)(Wu_bf + (size_t)l * D * D), bu + (size_t)l * D, h, h, mirror,
            N_NODES);
    }
}